// Round 5
// baseline (434.109 us; speedup 1.0000x reference)
//
#include <hip/hip_runtime.h>
#include <hip/hip_bf16.h>
#include <stdint.h>

#define B_ 2
#define S_ 2048
#define D_ 2048
#define H_ 16
#define HD_ 128
#define N3_ 6144

typedef __attribute__((ext_vector_type(8))) short short8;
typedef __attribute__((ext_vector_type(4))) float f32x4;
typedef __hip_bfloat16 bf16;

// ---------------- cast fp32 -> bf16 (vectorized) ----------------
__global__ void cast_bf16_kernel(const float* __restrict__ in, bf16* __restrict__ out, int n4) {
  int i = blockIdx.x * blockDim.x + threadIdx.x;
  if (i >= n4) return;
  float4 v = ((const float4*)in)[i];
  bf16 a = __float2bfloat16(v.x), b = __float2bfloat16(v.y);
  bf16 c = __float2bfloat16(v.z), d = __float2bfloat16(v.w);
  ushort4 o;
  o.x = *(unsigned short*)&a; o.y = *(unsigned short*)&b;
  o.z = *(unsigned short*)&c; o.w = *(unsigned short*)&d;
  ((ushort4*)out)[i] = o;
}

// ---------------- transpose + cast fp32 -> bf16 ----------------
__global__ void transpose_cast_kernel(const float* __restrict__ in, bf16* __restrict__ out,
                                      int R, int C) {
  __shared__ float tile[32][33];
  int c0 = blockIdx.x * 32, r0 = blockIdx.y * 32;
  int tx = threadIdx.x, ty = threadIdx.y;  // tx<32, ty<8
#pragma unroll
  for (int i = 0; i < 4; i++)
    tile[ty + i * 8][tx] = in[(size_t)(r0 + ty + i * 8) * C + c0 + tx];
  __syncthreads();
#pragma unroll
  for (int i = 0; i < 4; i++) {
    int oc = ty + i * 8;
    out[(size_t)(c0 + oc) * R + r0 + tx] = __float2bfloat16(tile[tx][oc]);
  }
}

// ---------------- bf16 MFMA GEMM: C(MxN) = A(MxK) @ Bt(NxK)^T ----------------
// BK=64, XOR-chunk-swizzled LDS (R4 version, unchanged).
__device__ __forceinline__ void store_c(float* p, float v) { *p = v; }
__device__ __forceinline__ void store_c(bf16* p, float v) { *p = __float2bfloat16(v); }

template <typename CT>
__global__ __launch_bounds__(256, 2) void gemm_bt_kernel(
    const bf16* __restrict__ A, const bf16* __restrict__ Bt, CT* __restrict__ C,
    int M, int N, int K) {
  __shared__ bf16 a_lds[128 * 64];  // 16 KB, swizzled
  __shared__ bf16 b_lds[128 * 64];  // 16 KB, swizzled
  int t = threadIdx.x;
  int lane = t & 63, w = t >> 6;
  int lane15 = lane & 15, quad = lane >> 4;
  int wm = w >> 1, wn = w & 1;
  int m0 = blockIdx.y * 128, n0 = blockIdx.x * 128;

  f32x4 acc[4][4];
#pragma unroll
  for (int i = 0; i < 4; i++)
#pragma unroll
    for (int j = 0; j < 4; j++) acc[i][j] = (f32x4){0.f, 0.f, 0.f, 0.f};

  const bf16* ga = A + (size_t)m0 * K;
  const bf16* gb = Bt + (size_t)n0 * K;

  int sr[4], sgc[4];
#pragma unroll
  for (int i = 0; i < 4; i++) {
    int ch = t + i * 256;
    sr[i] = ch >> 3;
    sgc[i] = (ch & 7) ^ (sr[i] & 7);
  }
  int sx = lane15 & 7;

  for (int kt = 0; kt < K; kt += 64) {
    __syncthreads();
#pragma unroll
    for (int i = 0; i < 4; i++) {
      int ch = t + i * 256;
      __builtin_amdgcn_global_load_lds(
          (const __attribute__((address_space(1))) void*)(ga + (size_t)sr[i] * K + kt + sgc[i] * 8),
          (__attribute__((address_space(3))) void*)(a_lds + ch * 8), 16, 0, 0);
      __builtin_amdgcn_global_load_lds(
          (const __attribute__((address_space(1))) void*)(gb + (size_t)sr[i] * K + kt + sgc[i] * 8),
          (__attribute__((address_space(3))) void*)(b_lds + ch * 8), 16, 0, 0);
    }
    __syncthreads();

#pragma unroll
    for (int ks = 0; ks < 2; ks++) {
      int slot = (ks * 4 + quad) ^ sx;
      short8 af[4], bfr[4];
#pragma unroll
      for (int mt = 0; mt < 4; mt++)
        af[mt] = *(const short8*)(a_lds + (wm * 64 + mt * 16 + lane15) * 64 + slot * 8);
#pragma unroll
      for (int nt = 0; nt < 4; nt++)
        bfr[nt] = *(const short8*)(b_lds + (wn * 64 + nt * 16 + lane15) * 64 + slot * 8);
#pragma unroll
      for (int mt = 0; mt < 4; mt++)
#pragma unroll
        for (int nt = 0; nt < 4; nt++)
          acc[mt][nt] = __builtin_amdgcn_mfma_f32_16x16x32_bf16(af[mt], bfr[nt], acc[mt][nt], 0, 0, 0);
    }
  }

#pragma unroll
  for (int mt = 0; mt < 4; mt++)
#pragma unroll
    for (int nt = 0; nt < 4; nt++)
#pragma unroll
      for (int r = 0; r < 4; r++) {
        int row = m0 + wm * 64 + mt * 16 + quad * 4 + r;
        int col = n0 + wn * 64 + nt * 16 + lane15;
        store_c(&C[(size_t)row * N + col], acc[mt][nt][r]);
      }
}

// ---------------- RoPE on q,k; writes per-head Q,K [b][h][s][hd] ----------------
__global__ void rope_qk_kernel(const bf16* __restrict__ qkv, const float* __restrict__ sinp,
                               const float* __restrict__ cosp, bf16* __restrict__ Q,
                               bf16* __restrict__ K) {
  int bs = blockIdx.x;
  int b = bs >> 11, s = bs & 2047;
  const bf16* row = qkv + (size_t)bs * N3_;
  for (int p = threadIdx.x; p < 2048; p += 256) {
    int g = p >> 10;
    int pp = p & 1023;
    int h = pp >> 6, i = pp & 63;
    float x1 = __bfloat162float(row[g * D_ + h * HD_ + i]);
    float x2 = __bfloat162float(row[g * D_ + h * HD_ + i + 64]);
    float sn = sinp[s * HD_ + i];
    float cs = cosp[s * HD_ + i];
    float o1 = x1 * cs - x2 * sn;
    float o2 = x2 * cs + x1 * sn;
    bf16* dst = (g == 0) ? Q : K;
    size_t base = (((size_t)b * H_ + h) * S_ + s) * HD_;
    dst[base + i] = __float2bfloat16(o1);
    dst[base + i + 64] = __float2bfloat16(o2);
  }
}

// ---------------- V -> Vt [b][h][hd][s] ----------------
__global__ void transpose_v_kernel(const bf16* __restrict__ qkv, bf16* __restrict__ Vt) {
  __shared__ __align__(16) bf16 tile[64][HD_ + 8];
  int bh = blockIdx.y;
  int b = bh >> 4, h = bh & 15;
  int s0 = blockIdx.x * 64;
  int t = threadIdx.x;
#pragma unroll
  for (int i = 0; i < 4; i++) {
    int ch = t + i * 256;
    int r = ch >> 4, cc = (ch & 15) * 8;
    *(uint4*)&tile[r][cc] =
        *(const uint4*)(qkv + (size_t)(b * S_ + s0 + r) * N3_ + 2 * D_ + h * HD_ + cc);
  }
  __syncthreads();
#pragma unroll
  for (int i = 0; i < 4; i++) {
    int ch = t + i * 256;
    int hd = ch >> 3, sl = (ch & 7) * 8;
    union { bf16 v[8]; uint4 u; } tmp;
#pragma unroll
    for (int j = 0; j < 8; j++) tmp.v[j] = tile[sl + j][hd];
    *(uint4*)(Vt + (((size_t)b * H_ + h) * HD_ + hd) * S_ + s0 + sl) = tmp.u;
  }
}

// ---------------- causal flash attention v4 ----------------
// Diagonal-paired: block (bh, y) sequentially does Q-tiles qi=y and qi=15-y
// -> every block runs exactly 34 kv-iters (perfect balance, grid=256=1/CU).
// K/V double-buffered in LDS via global_load_lds + raw s_barrier + manual
// s_waitcnt vmcnt(8): next tile's DMA streams behind current tile's compute.
__global__ __launch_bounds__(256, 1) void attn_kernel(
    const bf16* __restrict__ Q, const bf16* __restrict__ K, const bf16* __restrict__ Vt,
    bf16* __restrict__ Out) {
  __shared__ __align__(16) bf16 k_lds[2][64 * HD_];     // 2 x 16 KB, chunk-swizzled
  __shared__ __align__(16) bf16 v_lds[2][HD_ * 64];     // 2 x 16 KB, chunk-swizzled
  __shared__ __align__(16) bf16 p_lds[4][32][64 + 8];   // 18.4 KB (wave-private, padded)
  const float SCALE_LOG2 = 0.08838834764831845f * 1.4426950408889634f;  // 1/sqrt(128)*log2(e)

  int bh = blockIdx.x;  // bh fastest -> bh%8 fixes XCD; 4 bh/XCD -> K/V fits 4MB L2
  int b = bh >> 4, h = bh & 15;
  int t = threadIdx.x, w = t >> 6, lane = t & 63;
  int lane15 = lane & 15, quad = lane >> 4;

  const bf16* Qb = Q + ((size_t)b * H_ + h) * S_ * HD_;
  const bf16* Kb = K + ((size_t)b * H_ + h) * S_ * HD_;
  const bf16* Vb = Vt + ((size_t)b * H_ + h) * HD_ * S_;

  // staging address precompute (XOR chunk swizzle, as R4)
  int kr[4], kgc[4], vr[4], vgc[4];
#pragma unroll
  for (int i = 0; i < 4; i++) {
    int ch = t + i * 256;
    kr[i] = ch >> 4; kgc[i] = (ch & 15) ^ (kr[i] & 15);
    vr[i] = ch >> 3; vgc[i] = (ch & 7) ^ (vr[i] & 7);
  }

  auto issue_kv = [&](int kv0, int bufi) {
#pragma unroll
    for (int i = 0; i < 4; i++) {
      int ch = t + i * 256;
      __builtin_amdgcn_global_load_lds(
          (const __attribute__((address_space(1))) void*)(Kb + (size_t)(kv0 + kr[i]) * HD_ + kgc[i] * 8),
          (__attribute__((address_space(3))) void*)(&k_lds[bufi][ch * 8]), 16, 0, 0);
      __builtin_amdgcn_global_load_lds(
          (const __attribute__((address_space(1))) void*)(Vb + (size_t)vr[i] * S_ + kv0 + vgc[i] * 8),
          (__attribute__((address_space(3))) void*)(&v_lds[bufi][ch * 8]), 16, 0, 0);
    }
  };

#pragma unroll 1
  for (int ph = 0; ph < 2; ph++) {
    int qi = ph ? (15 - (int)blockIdx.y) : (int)blockIdx.y;
    int q0 = qi * 128;
    int ntiles = 2 * qi + 2;

    // load Q A-fragments for 2 m-tiles
    short8 qf[2][4];
#pragma unroll
    for (int mt = 0; mt < 2; mt++) {
      int qrow = q0 + w * 32 + mt * 16 + lane15;
#pragma unroll
      for (int k0 = 0; k0 < 4; k0++)
        qf[mt][k0] = *(const short8*)(Qb + (size_t)qrow * HD_ + k0 * 32 + quad * 8);
    }

    f32x4 o_acc[2][8];
#pragma unroll
    for (int mt = 0; mt < 2; mt++)
#pragma unroll
      for (int i = 0; i < 8; i++) o_acc[mt][i] = (f32x4){0.f, 0.f, 0.f, 0.f};
    float m_run[2][4], l_run[2][4];
#pragma unroll
    for (int mt = 0; mt < 2; mt++)
#pragma unroll
      for (int r = 0; r < 4; r++) { m_run[mt][r] = -1e30f; l_run[mt][r] = 0.f; }
    int row_base[2];
    row_base[0] = q0 + w * 32 + quad * 4;
    row_base[1] = q0 + w * 32 + 16 + quad * 4;

    issue_kv(0, 0);  // prologue: tile 0 -> buf 0

#pragma unroll 1
    for (int tk = 0; tk < ntiles; tk++) {
      int cur = tk & 1;
      int kv0 = tk * 64;
      if (tk + 1 < ntiles) {
        issue_kv(kv0 + 64, cur ^ 1);                 // next tile streams during compute
        __builtin_amdgcn_s_waitcnt(0xF78);           // vmcnt(8): tile tk landed, next in flight
      } else {
        __builtin_amdgcn_s_waitcnt(0xF70);           // vmcnt(0)
      }
      __builtin_amdgcn_s_barrier();                  // tile tk visible to all waves

      const bf16* kb = k_lds[cur];
      const bf16* vb = v_lds[cur];
      bool masked = (tk >= 2 * qi);

#pragma unroll
      for (int mt = 0; mt < 2; mt++) {
        f32x4 s_acc[4];
#pragma unroll
        for (int nt = 0; nt < 4; nt++) {
          f32x4 acc = (f32x4){0.f, 0.f, 0.f, 0.f};
#pragma unroll
          for (int k0 = 0; k0 < 4; k0++) {
            int r2 = nt * 16 + lane15;
            int cch = (k0 * 4 + quad) ^ (r2 & 15);
            short8 kf = *(const short8*)(kb + r2 * HD_ + cch * 8);
            acc = __builtin_amdgcn_mfma_f32_16x16x32_bf16(qf[mt][k0], kf, acc, 0, 0, 0);
          }
          s_acc[nt] = acc;
        }

        float p[4][4];
        float rowmax[4] = {-1e30f, -1e30f, -1e30f, -1e30f};
#pragma unroll
        for (int nt = 0; nt < 4; nt++) {
          int col = kv0 + nt * 16 + lane15;
#pragma unroll
          for (int r = 0; r < 4; r++) {
            float v = s_acc[nt][r] * SCALE_LOG2;
            if (masked && col > row_base[mt] + r) v = -1e30f;
            p[nt][r] = v;
            rowmax[r] = fmaxf(rowmax[r], v);
          }
        }
        float alpha[4];
#pragma unroll
        for (int r = 0; r < 4; r++) {
          float v = rowmax[r];
          v = fmaxf(v, __shfl_xor(v, 1));
          v = fmaxf(v, __shfl_xor(v, 2));
          v = fmaxf(v, __shfl_xor(v, 4));
          v = fmaxf(v, __shfl_xor(v, 8));
          float mnew = fmaxf(m_run[mt][r], v);
          alpha[r] = __builtin_amdgcn_exp2f(m_run[mt][r] - mnew);
          m_run[mt][r] = mnew;
        }
#pragma unroll
        for (int r = 0; r < 4; r++) {
          float lsum = 0.f;
#pragma unroll
          for (int nt = 0; nt < 4; nt++) {
            float e = __builtin_amdgcn_exp2f(p[nt][r] - m_run[mt][r]);
            p[nt][r] = e;
            lsum += e;
          }
          l_run[mt][r] = l_run[mt][r] * alpha[r] + lsum;
        }
#pragma unroll
        for (int on = 0; on < 8; on++) {
          f32x4 o = o_acc[mt][on];
          o[0] *= alpha[0]; o[1] *= alpha[1]; o[2] *= alpha[2]; o[3] *= alpha[3];
          o_acc[mt][on] = o;
        }
        // P (C-layout) -> wave-private LDS (same-wave DS ordering, no barrier)
#pragma unroll
        for (int nt = 0; nt < 4; nt++)
#pragma unroll
          for (int r = 0; r < 4; r++)
            p_lds[w][mt * 16 + quad * 4 + r][nt * 16 + lane15] = __float2bfloat16(p[nt][r]);
      }

#pragma unroll
      for (int mt = 0; mt < 2; mt++)
#pragma unroll
        for (int k0 = 0; k0 < 2; k0++) {
          short8 pf = *(const short8*)&p_lds[w][mt * 16 + lane15][k0 * 32 + quad * 8];
#pragma unroll
          for (int on = 0; on < 8; on++) {
            int rv = on * 16 + lane15;
            int cch = (k0 * 4 + quad) ^ (rv & 7);
            short8 vf = *(const short8*)(v_lds[cur] + rv * 64 + cch * 8);
            o_acc[mt][on] = __builtin_amdgcn_mfma_f32_16x16x32_bf16(pf, vf, o_acc[mt][on], 0, 0, 0);
          }
        }

      __builtin_amdgcn_s_barrier();  // all waves done reading buf[cur] before next DMA overwrites
    }

    // finalize phase
#pragma unroll
    for (int mt = 0; mt < 2; mt++) {
#pragma unroll
      for (int r = 0; r < 4; r++) {
        float v = l_run[mt][r];
        v += __shfl_xor(v, 1);
        v += __shfl_xor(v, 2);
        v += __shfl_xor(v, 4);
        v += __shfl_xor(v, 8);
        l_run[mt][r] = 1.f / v;
      }
#pragma unroll
      for (int on = 0; on < 8; on++)
#pragma unroll
        for (int r = 0; r < 4; r++) {
          int s = row_base[mt] + r;
          Out[((size_t)(b * S_ + s)) * D_ + h * HD_ + on * 16 + lane15] =
              __float2bfloat16(o_acc[mt][on][r] * l_run[mt][r]);
        }
    }
  }
}

// ---------------- launcher ----------------
extern "C" void kernel_launch(void* const* d_in, const int* in_sizes, int n_in,
                              void* d_out, int out_size, void* d_ws, size_t ws_size,
                              hipStream_t stream) {
  const float* x = (const float*)d_in[0];
  const float* sinp = (const float*)d_in[2];
  const float* cosp = (const float*)d_in[3];
  const float* Wqkv = (const float*)d_in[4];
  const float* Wproj = (const float*)d_in[5];
  float* out = (float*)d_out;

  char* ws = (char*)d_ws;
  bf16* x_bf = (bf16*)ws;    ws += (size_t)B_ * S_ * D_ * 2;
  bf16* wqkv_t = (bf16*)ws;  ws += (size_t)N3_ * D_ * 2;
  bf16* wproj_t = (bf16*)ws; ws += (size_t)D_ * D_ * 2;
  bf16* qkv = (bf16*)ws;     ws += (size_t)B_ * S_ * N3_ * 2;
  bf16* Qp = (bf16*)ws;      ws += (size_t)B_ * S_ * D_ * 2;
  bf16* Kp = (bf16*)ws;      ws += (size_t)B_ * S_ * D_ * 2;
  bf16* Vt = (bf16*)ws;      ws += (size_t)B_ * S_ * D_ * 2;
  bf16* attn = (bf16*)ws;    ws += (size_t)B_ * S_ * D_ * 2;

  int nx4 = B_ * S_ * D_ / 4;
  cast_bf16_kernel<<<nx4 / 256, 256, 0, stream>>>(x, x_bf, nx4);
  transpose_cast_kernel<<<dim3(N3_ / 32, D_ / 32), dim3(32, 8), 0, stream>>>(Wqkv, wqkv_t, D_, N3_);
  transpose_cast_kernel<<<dim3(D_ / 32, D_ / 32), dim3(32, 8), 0, stream>>>(Wproj, wproj_t, D_, D_);

  gemm_bt_kernel<bf16><<<dim3(N3_ / 128, (B_ * S_) / 128), 256, 0, stream>>>(
      x_bf, wqkv_t, qkv, B_ * S_, N3_, D_);

  rope_qk_kernel<<<B_ * S_, 256, 0, stream>>>(qkv, sinp, cosp, Qp, Kp);
  transpose_v_kernel<<<dim3(S_ / 64, B_ * H_), 256, 0, stream>>>(qkv, Vt);

  attn_kernel<<<dim3(B_ * H_, S_ / 128 / 2), 256, 0, stream>>>(Qp, Kp, Vt, attn);

  gemm_bt_kernel<float><<<dim3(D_ / 128, (B_ * S_) / 128), 256, 0, stream>>>(
      attn, wproj_t, out, B_ * S_, D_, D_);
}

// Round 6
// 388.197 us; speedup vs baseline: 1.1183x; 1.1183x over previous
//
#include <hip/hip_runtime.h>
#include <hip/hip_bf16.h>
#include <stdint.h>

#define B_ 2
#define S_ 2048
#define D_ 2048
#define H_ 16
#define HD_ 128
#define N3_ 6144

typedef __attribute__((ext_vector_type(8))) short short8;
typedef __attribute__((ext_vector_type(4))) float f32x4;
typedef __hip_bfloat16 bf16;

// ---------------- cast fp32 -> bf16 (vectorized) ----------------
__global__ void cast_bf16_kernel(const float* __restrict__ in, bf16* __restrict__ out, int n4) {
  int i = blockIdx.x * blockDim.x + threadIdx.x;
  if (i >= n4) return;
  float4 v = ((const float4*)in)[i];
  bf16 a = __float2bfloat16(v.x), b = __float2bfloat16(v.y);
  bf16 c = __float2bfloat16(v.z), d = __float2bfloat16(v.w);
  ushort4 o;
  o.x = *(unsigned short*)&a; o.y = *(unsigned short*)&b;
  o.z = *(unsigned short*)&c; o.w = *(unsigned short*)&d;
  ((ushort4*)out)[i] = o;
}

// ---------------- transpose + cast fp32 -> bf16 ----------------
__global__ void transpose_cast_kernel(const float* __restrict__ in, bf16* __restrict__ out,
                                      int R, int C) {
  __shared__ float tile[32][33];
  int c0 = blockIdx.x * 32, r0 = blockIdx.y * 32;
  int tx = threadIdx.x, ty = threadIdx.y;  // tx<32, ty<8
#pragma unroll
  for (int i = 0; i < 4; i++)
    tile[ty + i * 8][tx] = in[(size_t)(r0 + ty + i * 8) * C + c0 + tx];
  __syncthreads();
#pragma unroll
  for (int i = 0; i < 4; i++) {
    int oc = ty + i * 8;
    out[(size_t)(c0 + oc) * R + r0 + tx] = __float2bfloat16(tile[tx][oc]);
  }
}

// ---------------- bf16 MFMA GEMM: C(MxN) = A(MxK) @ Bt(NxK)^T ----------------
// BK=64, XOR-chunk-swizzled LDS (R4 version, unchanged).
__device__ __forceinline__ void store_c(float* p, float v) { *p = v; }
__device__ __forceinline__ void store_c(bf16* p, float v) { *p = __float2bfloat16(v); }

template <typename CT>
__global__ __launch_bounds__(256, 2) void gemm_bt_kernel(
    const bf16* __restrict__ A, const bf16* __restrict__ Bt, CT* __restrict__ C,
    int M, int N, int K) {
  __shared__ bf16 a_lds[128 * 64];  // 16 KB, swizzled
  __shared__ bf16 b_lds[128 * 64];  // 16 KB, swizzled
  int t = threadIdx.x;
  int lane = t & 63, w = t >> 6;
  int lane15 = lane & 15, quad = lane >> 4;
  int wm = w >> 1, wn = w & 1;
  int m0 = blockIdx.y * 128, n0 = blockIdx.x * 128;

  f32x4 acc[4][4];
#pragma unroll
  for (int i = 0; i < 4; i++)
#pragma unroll
    for (int j = 0; j < 4; j++) acc[i][j] = (f32x4){0.f, 0.f, 0.f, 0.f};

  const bf16* ga = A + (size_t)m0 * K;
  const bf16* gb = Bt + (size_t)n0 * K;

  int sr[4], sgc[4];
#pragma unroll
  for (int i = 0; i < 4; i++) {
    int ch = t + i * 256;
    sr[i] = ch >> 3;
    sgc[i] = (ch & 7) ^ (sr[i] & 7);
  }
  int sx = lane15 & 7;

  for (int kt = 0; kt < K; kt += 64) {
    __syncthreads();
#pragma unroll
    for (int i = 0; i < 4; i++) {
      int ch = t + i * 256;
      __builtin_amdgcn_global_load_lds(
          (const __attribute__((address_space(1))) void*)(ga + (size_t)sr[i] * K + kt + sgc[i] * 8),
          (__attribute__((address_space(3))) void*)(a_lds + ch * 8), 16, 0, 0);
      __builtin_amdgcn_global_load_lds(
          (const __attribute__((address_space(1))) void*)(gb + (size_t)sr[i] * K + kt + sgc[i] * 8),
          (__attribute__((address_space(3))) void*)(b_lds + ch * 8), 16, 0, 0);
    }
    __syncthreads();

#pragma unroll
    for (int ks = 0; ks < 2; ks++) {
      int slot = (ks * 4 + quad) ^ sx;
      short8 af[4], bfr[4];
#pragma unroll
      for (int mt = 0; mt < 4; mt++)
        af[mt] = *(const short8*)(a_lds + (wm * 64 + mt * 16 + lane15) * 64 + slot * 8);
#pragma unroll
      for (int nt = 0; nt < 4; nt++)
        bfr[nt] = *(const short8*)(b_lds + (wn * 64 + nt * 16 + lane15) * 64 + slot * 8);
#pragma unroll
      for (int mt = 0; mt < 4; mt++)
#pragma unroll
        for (int nt = 0; nt < 4; nt++)
          acc[mt][nt] = __builtin_amdgcn_mfma_f32_16x16x32_bf16(af[mt], bfr[nt], acc[mt][nt], 0, 0, 0);
    }
  }

#pragma unroll
  for (int mt = 0; mt < 4; mt++)
#pragma unroll
    for (int nt = 0; nt < 4; nt++)
#pragma unroll
      for (int r = 0; r < 4; r++) {
        int row = m0 + wm * 64 + mt * 16 + quad * 4 + r;
        int col = n0 + wn * 64 + nt * 16 + lane15;
        store_c(&C[(size_t)row * N + col], acc[mt][nt][r]);
      }
}

// ---------------- RoPE on q,k; writes per-head Q,K [b][h][s][hd] ----------------
__global__ void rope_qk_kernel(const bf16* __restrict__ qkv, const float* __restrict__ sinp,
                               const float* __restrict__ cosp, bf16* __restrict__ Q,
                               bf16* __restrict__ K) {
  int bs = blockIdx.x;
  int b = bs >> 11, s = bs & 2047;
  const bf16* row = qkv + (size_t)bs * N3_;
  for (int p = threadIdx.x; p < 2048; p += 256) {
    int g = p >> 10;
    int pp = p & 1023;
    int h = pp >> 6, i = pp & 63;
    float x1 = __bfloat162float(row[g * D_ + h * HD_ + i]);
    float x2 = __bfloat162float(row[g * D_ + h * HD_ + i + 64]);
    float sn = sinp[s * HD_ + i];
    float cs = cosp[s * HD_ + i];
    float o1 = x1 * cs - x2 * sn;
    float o2 = x2 * cs + x1 * sn;
    bf16* dst = (g == 0) ? Q : K;
    size_t base = (((size_t)b * H_ + h) * S_ + s) * HD_;
    dst[base + i] = __float2bfloat16(o1);
    dst[base + i + 64] = __float2bfloat16(o2);
  }
}

// ---------------- V -> Vt [b][h][hd][s] ----------------
__global__ void transpose_v_kernel(const bf16* __restrict__ qkv, bf16* __restrict__ Vt) {
  __shared__ __align__(16) bf16 tile[64][HD_ + 8];
  int bh = blockIdx.y;
  int b = bh >> 4, h = bh & 15;
  int s0 = blockIdx.x * 64;
  int t = threadIdx.x;
#pragma unroll
  for (int i = 0; i < 4; i++) {
    int ch = t + i * 256;
    int r = ch >> 4, cc = (ch & 15) * 8;
    *(uint4*)&tile[r][cc] =
        *(const uint4*)(qkv + (size_t)(b * S_ + s0 + r) * N3_ + 2 * D_ + h * HD_ + cc);
  }
  __syncthreads();
#pragma unroll
  for (int i = 0; i < 4; i++) {
    int ch = t + i * 256;
    int hd = ch >> 3, sl = (ch & 7) * 8;
    union { bf16 v[8]; uint4 u; } tmp;
#pragma unroll
    for (int j = 0; j < 8; j++) tmp.v[j] = tile[sl + j][hd];
    *(uint4*)(Vt + (((size_t)b * H_ + h) * HD_ + hd) * S_ + s0 + sl) = tmp.u;
  }
}

// ---------------- causal flash attention v5 ----------------
// Diagonal-paired (perfect balance, grid=256=1/CU) + 512 threads / 8 waves
// (2 waves/SIMD: one wave's MFMA overlaps another's VALU/ds). Wave w owns
// Q-rows w*16..w*16+15. K/V double-buffered via global_load_lds + raw
// s_barrier + manual s_waitcnt vmcnt(4) (next tile's 4 loads stay in flight).
__global__ __launch_bounds__(512, 1) void attn_kernel(
    const bf16* __restrict__ Q, const bf16* __restrict__ K, const bf16* __restrict__ Vt,
    bf16* __restrict__ Out) {
  __shared__ __align__(16) bf16 k_lds[2][64 * HD_];     // 2 x 16 KB, chunk-swizzled
  __shared__ __align__(16) bf16 v_lds[2][HD_ * 64];     // 2 x 16 KB, chunk-swizzled
  __shared__ __align__(16) bf16 p_lds[8][16][64 + 8];   // 18.4 KB (wave-private, padded)
  const float SCALE_LOG2 = 0.08838834764831845f * 1.4426950408889634f;  // 1/sqrt(128)*log2(e)

  int bh = blockIdx.x;  // bh fastest -> bh%8 fixes XCD; K/V working set ~L2-resident
  int b = bh >> 4, h = bh & 15;
  int t = threadIdx.x, w = t >> 6, lane = t & 63;
  int lane15 = lane & 15, quad = lane >> 4;

  const bf16* Qb = Q + ((size_t)b * H_ + h) * S_ * HD_;
  const bf16* Kb = K + ((size_t)b * H_ + h) * S_ * HD_;
  const bf16* Vb = Vt + ((size_t)b * H_ + h) * HD_ * S_;

  // staging address precompute (XOR chunk swizzle); 1024 chunks/tile, 2/thread
  int kr[2], kgc[2], vr[2], vgc[2];
#pragma unroll
  for (int i = 0; i < 2; i++) {
    int ch = t + i * 512;
    kr[i] = ch >> 4; kgc[i] = (ch & 15) ^ (kr[i] & 15);
    vr[i] = ch >> 3; vgc[i] = (ch & 7) ^ (vr[i] & 7);
  }

  auto issue_kv = [&](int kv0, int bufi) {
#pragma unroll
    for (int i = 0; i < 2; i++) {
      int ch = t + i * 512;
      __builtin_amdgcn_global_load_lds(
          (const __attribute__((address_space(1))) void*)(Kb + (size_t)(kv0 + kr[i]) * HD_ + kgc[i] * 8),
          (__attribute__((address_space(3))) void*)(&k_lds[bufi][ch * 8]), 16, 0, 0);
      __builtin_amdgcn_global_load_lds(
          (const __attribute__((address_space(1))) void*)(Vb + (size_t)vr[i] * S_ + kv0 + vgc[i] * 8),
          (__attribute__((address_space(3))) void*)(&v_lds[bufi][ch * 8]), 16, 0, 0);
    }
  };

#pragma unroll 1
  for (int ph = 0; ph < 2; ph++) {
    int qi = ph ? (15 - (int)blockIdx.y) : (int)blockIdx.y;
    int q0 = qi * 128;
    int ntiles = 2 * qi + 2;

    // this wave's 16 Q rows as A-fragments
    short8 qf[4];
    {
      int qrow = q0 + w * 16 + lane15;
#pragma unroll
      for (int k0 = 0; k0 < 4; k0++)
        qf[k0] = *(const short8*)(Qb + (size_t)qrow * HD_ + k0 * 32 + quad * 8);
    }

    f32x4 o_acc[8];
#pragma unroll
    for (int i = 0; i < 8; i++) o_acc[i] = (f32x4){0.f, 0.f, 0.f, 0.f};
    float m_run[4], l_run[4];
#pragma unroll
    for (int r = 0; r < 4; r++) { m_run[r] = -1e30f; l_run[r] = 0.f; }
    int row_base = q0 + w * 16 + quad * 4;

    issue_kv(0, 0);  // prologue: tile 0 -> buf 0

#pragma unroll 1
    for (int tk = 0; tk < ntiles; tk++) {
      int cur = tk & 1;
      int kv0 = tk * 64;
      if (tk + 1 < ntiles) {
        issue_kv(kv0 + 64, cur ^ 1);                 // next tile streams behind compute
        __builtin_amdgcn_s_waitcnt(0xF74);           // vmcnt(4): tile tk landed, next in flight
      } else {
        __builtin_amdgcn_s_waitcnt(0xF70);           // vmcnt(0)
      }
      __builtin_amdgcn_s_barrier();                  // tile tk visible to all waves

      const bf16* kb = k_lds[cur];
      bool masked = (tk >= 2 * qi);

      // S = Q @ K^T (16x64)
      f32x4 s_acc[4];
#pragma unroll
      for (int nt = 0; nt < 4; nt++) {
        f32x4 acc = (f32x4){0.f, 0.f, 0.f, 0.f};
#pragma unroll
        for (int k0 = 0; k0 < 4; k0++) {
          int r2 = nt * 16 + lane15;
          int cch = (k0 * 4 + quad) ^ (r2 & 15);
          short8 kf = *(const short8*)(kb + r2 * HD_ + cch * 8);
          acc = __builtin_amdgcn_mfma_f32_16x16x32_bf16(qf[k0], kf, acc, 0, 0, 0);
        }
        s_acc[nt] = acc;
      }

      float p[4][4];
      float rowmax[4] = {-1e30f, -1e30f, -1e30f, -1e30f};
#pragma unroll
      for (int nt = 0; nt < 4; nt++) {
        int col = kv0 + nt * 16 + lane15;
#pragma unroll
        for (int r = 0; r < 4; r++) {
          float v = s_acc[nt][r] * SCALE_LOG2;
          if (masked && col > row_base + r) v = -1e30f;
          p[nt][r] = v;
          rowmax[r] = fmaxf(rowmax[r], v);
        }
      }
      float alpha[4];
#pragma unroll
      for (int r = 0; r < 4; r++) {
        float v = rowmax[r];
        v = fmaxf(v, __shfl_xor(v, 1));
        v = fmaxf(v, __shfl_xor(v, 2));
        v = fmaxf(v, __shfl_xor(v, 4));
        v = fmaxf(v, __shfl_xor(v, 8));
        float mnew = fmaxf(m_run[r], v);
        alpha[r] = __builtin_amdgcn_exp2f(m_run[r] - mnew);
        m_run[r] = mnew;
      }
#pragma unroll
      for (int r = 0; r < 4; r++) {
        float lsum = 0.f;
#pragma unroll
        for (int nt = 0; nt < 4; nt++) {
          float e = __builtin_amdgcn_exp2f(p[nt][r] - m_run[r]);
          p[nt][r] = e;
          lsum += e;
        }
        l_run[r] = l_run[r] * alpha[r] + lsum;
      }
#pragma unroll
      for (int on = 0; on < 8; on++) {
        f32x4 o = o_acc[on];
        o[0] *= alpha[0]; o[1] *= alpha[1]; o[2] *= alpha[2]; o[3] *= alpha[3];
        o_acc[on] = o;
      }
      // P (C-layout) -> wave-private LDS (same-wave DS ordering, no barrier)
#pragma unroll
      for (int nt = 0; nt < 4; nt++)
#pragma unroll
        for (int r = 0; r < 4; r++)
          p_lds[w][quad * 4 + r][nt * 16 + lane15] = __float2bfloat16(p[nt][r]);

      // O += P @ V
#pragma unroll
      for (int k0 = 0; k0 < 2; k0++) {
        short8 pf = *(const short8*)&p_lds[w][lane15][k0 * 32 + quad * 8];
#pragma unroll
        for (int on = 0; on < 8; on++) {
          int rv = on * 16 + lane15;
          int cch = (k0 * 4 + quad) ^ (rv & 7);
          short8 vf = *(const short8*)(v_lds[cur] + rv * 64 + cch * 8);
          o_acc[on] = __builtin_amdgcn_mfma_f32_16x16x32_bf16(pf, vf, o_acc[on], 0, 0, 0);
        }
      }

      __builtin_amdgcn_s_barrier();  // all waves done with buf[cur^1]'s predecessor before DMA reuse
    }

    // finalize phase
#pragma unroll
    for (int r = 0; r < 4; r++) {
      float v = l_run[r];
      v += __shfl_xor(v, 1);
      v += __shfl_xor(v, 2);
      v += __shfl_xor(v, 4);
      v += __shfl_xor(v, 8);
      l_run[r] = 1.f / v;
    }
#pragma unroll
    for (int on = 0; on < 8; on++)
#pragma unroll
      for (int r = 0; r < 4; r++) {
        int s = row_base + r;
        Out[((size_t)(b * S_ + s)) * D_ + h * HD_ + on * 16 + lane15] =
            __float2bfloat16(o_acc[on][r] * l_run[r]);
      }
  }
}

// ---------------- launcher ----------------
extern "C" void kernel_launch(void* const* d_in, const int* in_sizes, int n_in,
                              void* d_out, int out_size, void* d_ws, size_t ws_size,
                              hipStream_t stream) {
  const float* x = (const float*)d_in[0];
  const float* sinp = (const float*)d_in[2];
  const float* cosp = (const float*)d_in[3];
  const float* Wqkv = (const float*)d_in[4];
  const float* Wproj = (const float*)d_in[5];
  float* out = (float*)d_out;

  char* ws = (char*)d_ws;
  bf16* x_bf = (bf16*)ws;    ws += (size_t)B_ * S_ * D_ * 2;
  bf16* wqkv_t = (bf16*)ws;  ws += (size_t)N3_ * D_ * 2;
  bf16* wproj_t = (bf16*)ws; ws += (size_t)D_ * D_ * 2;
  bf16* qkv = (bf16*)ws;     ws += (size_t)B_ * S_ * N3_ * 2;
  bf16* Qp = (bf16*)ws;      ws += (size_t)B_ * S_ * D_ * 2;
  bf16* Kp = (bf16*)ws;      ws += (size_t)B_ * S_ * D_ * 2;
  bf16* Vt = (bf16*)ws;      ws += (size_t)B_ * S_ * D_ * 2;
  bf16* attn = (bf16*)ws;    ws += (size_t)B_ * S_ * D_ * 2;

  int nx4 = B_ * S_ * D_ / 4;
  cast_bf16_kernel<<<nx4 / 256, 256, 0, stream>>>(x, x_bf, nx4);
  transpose_cast_kernel<<<dim3(N3_ / 32, D_ / 32), dim3(32, 8), 0, stream>>>(Wqkv, wqkv_t, D_, N3_);
  transpose_cast_kernel<<<dim3(D_ / 32, D_ / 32), dim3(32, 8), 0, stream>>>(Wproj, wproj_t, D_, D_);

  gemm_bt_kernel<bf16><<<dim3(N3_ / 128, (B_ * S_) / 128), 256, 0, stream>>>(
      x_bf, wqkv_t, qkv, B_ * S_, N3_, D_);

  rope_qk_kernel<<<B_ * S_, 256, 0, stream>>>(qkv, sinp, cosp, Qp, Kp);
  transpose_v_kernel<<<dim3(S_ / 64, B_ * H_), 256, 0, stream>>>(qkv, Vt);

  attn_kernel<<<dim3(B_ * H_, S_ / 128 / 2), 512, 0, stream>>>(Qp, Kp, Vt, attn);

  gemm_bt_kernel<float><<<dim3(D_ / 128, (B_ * S_) / 128), 256, 0, stream>>>(
      attn, wproj_t, out, B_ * S_, D_, D_);
}